// Round 7
// baseline (229.658 us; speedup 1.0000x reference)
//
#include <hip/hip_runtime.h>
#include <hip/hip_bf16.h>

// KVMN forward, 2-kernel pipeline:
//  1) prep  : grid-partitioned fusion —
//             blocks [0,64)  : phaseA  u[b,s,m] = <hs[b,s], key[wseq[b,m]]> via
//                              MFMA bf16 (fp32 inputs converted in-register)
//             blocks [64, +) : value_table fp32 -> bf16 stream convert
//             (no dependency between the two halves)
//  2) gather: delta = exp(u/sqrt(H))*clip(mask); o = sum_m delta*vt[row]; normalize
//
// B=4 S=512 M=128 H=768.

constexpr int B = 4, S = 512, M = 128, H = 768;
constexpr int C4 = H / 4;
constexpr int KEY_SIZE = 30000, VALUE_SIZE = 10000;

constexpr int VT_N = VALUE_SIZE * H;      // 7,680,000
constexpr int U_N  = B * S * M;           //   262,144

constexpr size_t VT_BYTES = (size_t)VT_N * 2;
constexpr size_t U_BYTES  = (size_t)U_N  * 4;
constexpr size_t WS_NEEDED = VT_BYTES + U_BYTES;      // ~16.4 MB

constexpr int VT_V4      = VT_N / 4;                  // 1,920,000 ushort4 items
constexpr int NB_PHASEA  = 64;                        // 64 blocks * 4 waves = 256 tiles
constexpr int NB_VT      = VT_V4 / 256;               // 7,500
constexpr int NB_PREP    = NB_PHASEA + NB_VT;

typedef short          bf16x8   __attribute__((ext_vector_type(8)));
typedef float          floatx4  __attribute__((ext_vector_type(4)));
typedef unsigned short ushort8v __attribute__((ext_vector_type(8)));

__device__ inline unsigned short f2bf(float f) {
    __hip_bfloat16 h = __float2bfloat16(f);           // RNE
    return *reinterpret_cast<unsigned short*>(&h);
}
__device__ inline float bf2f(unsigned short u) {
    return __uint_as_float((unsigned)u << 16);
}
__device__ inline ushort4 f4_to_bf4(float4 f) {
    ushort4 u; u.x = f2bf(f.x); u.y = f2bf(f.y); u.z = f2bf(f.z); u.w = f2bf(f.w);
    return u;
}
__device__ inline bf16x8 f8_to_bf8(float4 a, float4 b) {
    bf16x8 r;
    r[0] = (short)f2bf(a.x); r[1] = (short)f2bf(a.y);
    r[2] = (short)f2bf(a.z); r[3] = (short)f2bf(a.w);
    r[4] = (short)f2bf(b.x); r[5] = (short)f2bf(b.y);
    r[6] = (short)f2bf(b.z); r[7] = (short)f2bf(b.w);
    return r;
}

// ---- kernel 1: fused phaseA (MFMA from fp32) + value-table convert ----
__global__ __launch_bounds__(256) void prep_kernel(
    const float* __restrict__ vt,               // [VALUE_SIZE,H] fp32
    const float* __restrict__ kt,               // [KEY_SIZE,H]   fp32
    const float* __restrict__ hs,               // [B,S,H]        fp32
    const int*   __restrict__ wseq,             // [B,M]
    unsigned short* __restrict__ vt_bf,         // [VALUE_SIZE,H] bf16 out
    float*       __restrict__ u_ws)             // [B,S,M] fp32 out
{
    if (blockIdx.x >= NB_PHASEA) {
        // ---- value-table convert: one ushort4 per thread ----
        int i = (blockIdx.x - NB_PHASEA) * 256 + threadIdx.x;
        ((ushort4*)vt_bf)[i] = f4_to_bf4(((const float4*)vt)[i]);
        return;
    }

    // ---- phaseA: one 16x16 u-tile per wave ----
    const int lane = threadIdx.x & 63;
    const int wave = threadIdx.x >> 6;
    const int tile = blockIdx.x * 4 + wave;     // 0..255
    const int b    = tile >> 6;                 // 64 tiles per b
    const int r    = tile & 63;
    const int s0   = (r >> 3) << 4;             // hmm: 32 s-tiles * 8 m-tiles = 256 per b
    // NOTE: per b there are (S/16)*(M/16) = 32*8 = 256 tiles; with 256 total tiles
    // we need tile -> (b, s-tile, m-tile) over 4*256 = 1024 tiles. Use 1024 tiles:
    // re-derive below from a flat 0..1023 id built as blockIdx.x*4+wave with 256 blocks.
    (void)b; (void)r; (void)s0;

    // flat tile id must span 1024; NB_PHASEA*4 = 256, so each wave handles 4 tiles.
    const float inv_one = 1.0f; (void)inv_one;
    for (int rep = 0; rep < 4; ++rep) {
        const int tid  = tile + rep * 256;      // 0..1023
        const int bb   = tid >> 8;              // 256 tiles per b
        const int rr   = tid & 255;
        const int ss0  = (rr >> 3) << 4;        // s-tile * 16
        const int mm0  = (rr & 7) << 4;         // m-tile * 16
        const int l15  = lane & 15;
        const int quad = lane >> 4;

        const float* arow = hs + (size_t)(bb * S + ss0 + l15) * H + quad * 8;
        const int    krow = wseq[bb * M + mm0 + l15];
        const float* brow = kt + (size_t)krow * H + quad * 8;

        floatx4 acc = {0.f, 0.f, 0.f, 0.f};
        #pragma unroll 4
        for (int k = 0; k < H; k += 32) {
            const float4* ap = (const float4*)(arow + k);
            const float4* bp = (const float4*)(brow + k);
            bf16x8 af = f8_to_bf8(ap[0], ap[1]);
            bf16x8 bf = f8_to_bf8(bp[0], bp[1]);
            acc = __builtin_amdgcn_mfma_f32_16x16x32_bf16(af, bf, acc, 0, 0, 0);
        }
        // C/D: col(=m) = lane&15, row(=s) = quad*4 + reg
        float* up = u_ws + (size_t)(bb * S + ss0 + quad * 4) * M + mm0 + l15;
        up[0 * M] = acc[0];
        up[1 * M] = acc[1];
        up[2 * M] = acc[2];
        up[3 * M] = acc[3];
    }
}

// ---- kernel 2: gather + weighted sum + normalize ----
// 192 threads per (b,s). Thread owns 16B h-chunk c = t%96 and parity p = t/96;
// hot loop: 64 iterations of ONE global_load_dwordx4 + 8 cvt/FMA.
__global__ __launch_bounds__(192) void gather_kernel(
    const float* __restrict__ u_ws,             // [B,S,M]
    const int*   __restrict__ lvm,              // [B,S,M]
    const float* __restrict__ mask,             // [B,S,M]
    const unsigned short* __restrict__ vt_bf,   // [VALUE_SIZE,H]
    float*       __restrict__ out)              // [B,S,H]
{
    const int bs = blockIdx.x;
    const int t  = threadIdx.x;       // 0..191
    const int p  = t / 96;            // parity: which half of m
    const int c  = t - p * 96;        // 16B chunk index, 0..95

    __shared__ float delta_s[M];
    __shared__ int   row_s[M];
    __shared__ float merge_s[8][100]; // SoA: [elem][chunk], padded
    __shared__ float dsum_s;

    const float inv_temper = rsqrtf((float)H);
    if (t < M) {
        float u  = u_ws[(size_t)bs * M + t];
        float mk = mask[(size_t)bs * M + t];
        mk = fminf(fmaxf(mk, 0.f), 1.f);
        delta_s[t] = __expf(u * inv_temper) * mk;
        row_s[t]   = lvm[(size_t)bs * M + t];
    }
    __syncthreads();

    // wave 0: denominator (consumed after the epilogue barrier)
    if (t < 64) {
        float d = delta_s[t] + delta_s[t + 64];
        #pragma unroll
        for (int off = 1; off < 64; off <<= 1) d += __shfl_xor(d, off);
        if (t == 0) dsum_s = d + 1e-10f;
    }

    float a0 = 0.f, a1 = 0.f, a2 = 0.f, a3 = 0.f;
    float a4 = 0.f, a5 = 0.f, a6 = 0.f, a7 = 0.f;

    const unsigned short* base = vt_bf + c * 8;
    #pragma unroll 8
    for (int m = p; m < M; m += 2) {
        const float pm = delta_s[m];
        ushort8v v = *(const ushort8v*)(base + (size_t)row_s[m] * H);
        a0 += pm * bf2f(v[0]);
        a1 += pm * bf2f(v[1]);
        a2 += pm * bf2f(v[2]);
        a3 += pm * bf2f(v[3]);
        a4 += pm * bf2f(v[4]);
        a5 += pm * bf2f(v[5]);
        a6 += pm * bf2f(v[6]);
        a7 += pm * bf2f(v[7]);
    }

    if (p == 1) {
        merge_s[0][c] = a0; merge_s[1][c] = a1; merge_s[2][c] = a2; merge_s[3][c] = a3;
        merge_s[4][c] = a4; merge_s[5][c] = a5; merge_s[6][c] = a6; merge_s[7][c] = a7;
    }
    __syncthreads();

    if (p == 0) {
        const float inv_d = 1.0f / dsum_s;
        float4 r0, r1;
        r0.x = (a0 + merge_s[0][c]) * inv_d;
        r0.y = (a1 + merge_s[1][c]) * inv_d;
        r0.z = (a2 + merge_s[2][c]) * inv_d;
        r0.w = (a3 + merge_s[3][c]) * inv_d;
        r1.x = (a4 + merge_s[4][c]) * inv_d;
        r1.y = (a5 + merge_s[5][c]) * inv_d;
        r1.z = (a6 + merge_s[6][c]) * inv_d;
        r1.w = (a7 + merge_s[7][c]) * inv_d;
        float4* og = (float4*)(out + (size_t)bs * H + c * 8);
        og[0] = r0;
        og[1] = r1;
    }
}

// ---- fallback: fused fp32 (only if ws too small) ----
__global__ __launch_bounds__(192) void kvmn_fp32_kernel(
    const int*   __restrict__ word_seq,
    const float* __restrict__ hidden_state,
    const int*   __restrict__ lvm,
    const float* __restrict__ mask,
    const float* __restrict__ key_table,
    const float* __restrict__ value_table,
    float*       __restrict__ out)
{
    const int bs   = blockIdx.x;
    const int b    = bs / S;
    const int t    = threadIdx.x;
    const int lane = t & 63;
    const int wave = t >> 6;

    __shared__ float4 hs4_s[C4];
    __shared__ int    wseq_s[M];
    __shared__ int    row_s[M];
    __shared__ float  mask_s[M];
    __shared__ float4 obuf[3][C4];
    __shared__ float  dsum_s3[3];

    const float4* hs_g4 = (const float4*)(hidden_state + (size_t)bs * H);
    hs4_s[t] = hs_g4[t];
    if (t < M) {
        wseq_s[t] = word_seq[b * M + t];
        row_s[t]  = lvm[(size_t)bs * M + t];
        float mk  = mask[(size_t)bs * M + t];
        mask_s[t] = fminf(fmaxf(mk, 0.f), 1.f);
    }
    __syncthreads();

    const float4 h0 = hs4_s[lane];
    const float4 h1 = hs4_s[lane + 64];
    const float4 h2 = hs4_s[lane + 128];
    const float inv_temper = rsqrtf((float)H);
    const float4* kt4 = (const float4*)key_table;
    const float4* vt4 = (const float4*)value_table;

    float4 a0 = {0.f,0.f,0.f,0.f}, a1 = {0.f,0.f,0.f,0.f}, a2 = {0.f,0.f,0.f,0.f};
    float dsum = 0.f;

    #pragma unroll 2
    for (int m = wave; m < M; m += 3) {
        const float4* kr = kt4 + (size_t)wseq_s[m] * C4;
        const float4* vr = vt4 + (size_t)row_s[m]  * C4;
        const float4 k0 = kr[lane], k1 = kr[lane+64], k2 = kr[lane+128];
        const float4 v0 = vr[lane], v1 = vr[lane+64], v2 = vr[lane+128];
        float dot = h0.x*k0.x + h0.y*k0.y + h0.z*k0.z + h0.w*k0.w
                  + h1.x*k1.x + h1.y*k1.y + h1.z*k1.z + h1.w*k1.w
                  + h2.x*k2.x + h2.y*k2.y + h2.z*k2.z + h2.w*k2.w;
        #pragma unroll
        for (int off = 1; off < 64; off <<= 1) dot += __shfl_xor(dot, off);
        const float delta = __expf(dot * inv_temper) * mask_s[m];
        dsum += delta;
        a0.x += delta*v0.x; a0.y += delta*v0.y; a0.z += delta*v0.z; a0.w += delta*v0.w;
        a1.x += delta*v1.x; a1.y += delta*v1.y; a1.z += delta*v1.z; a1.w += delta*v1.w;
        a2.x += delta*v2.x; a2.y += delta*v2.y; a2.z += delta*v2.z; a2.w += delta*v2.w;
    }
    obuf[wave][lane] = a0; obuf[wave][lane+64] = a1; obuf[wave][lane+128] = a2;
    if (lane == 0) dsum_s3[wave] = dsum;
    __syncthreads();
    const float inv_d = 1.0f / (dsum_s3[0] + dsum_s3[1] + dsum_s3[2] + 1e-10f);
    const float4 r0 = obuf[0][t], r1 = obuf[1][t], r2 = obuf[2][t];
    float4 r;
    r.x = (r0.x+r1.x+r2.x)*inv_d; r.y = (r0.y+r1.y+r2.y)*inv_d;
    r.z = (r0.z+r1.z+r2.z)*inv_d; r.w = (r0.w+r1.w+r2.w)*inv_d;
    ((float4*)(out + (size_t)bs * H))[t] = r;
}

extern "C" void kernel_launch(void* const* d_in, const int* in_sizes, int n_in,
                              void* d_out, int out_size, void* d_ws, size_t ws_size,
                              hipStream_t stream) {
    const int*   word_seq    = (const int*)  d_in[0];
    const float* hidden      = (const float*)d_in[1];
    const int*   lvm         = (const int*)  d_in[2];
    const float* mask        = (const float*)d_in[3];
    const float* key_table   = (const float*)d_in[4];
    const float* value_table = (const float*)d_in[5];
    float* out = (float*)d_out;

    if (ws_size >= WS_NEEDED) {
        unsigned short* vt_bf = (unsigned short*)d_ws;
        float*          u_ws  = (float*)((char*)d_ws + VT_BYTES);

        prep_kernel<<<NB_PREP, 256, 0, stream>>>(
            value_table, key_table, hidden, word_seq, vt_bf, u_ws);
        gather_kernel<<<B * S, 192, 0, stream>>>(
            u_ws, lvm, mask, vt_bf, out);
    } else {
        kvmn_fp32_kernel<<<B * S, 192, 0, stream>>>(
            word_seq, hidden, lvm, mask, key_table, value_table, out);
    }
}

// Round 8
// 202.232 us; speedup vs baseline: 1.1356x; 1.1356x over previous
//
#include <hip/hip_runtime.h>
#include <hip/hip_bf16.h>

// KVMN forward, 2-kernel pipeline:
//  1) prep  : grid-partitioned fusion, balanced —
//             blocks [0,256)   : phaseA, ONE 16x16 u-tile per wave (1024 tiles),
//                                fp32 inputs converted to bf16 in-register, MFMA
//             blocks [256, +)  : value_table fp32 -> bf16 stream convert (16B stores)
//             phaseA blocks dispatch first and overlap under the convert stream.
//  2) gather: delta = exp(u/sqrt(H))*clip(mask); o = sum_m delta*vt[row]; normalize
//
// B=4 S=512 M=128 H=768.

constexpr int B = 4, S = 512, M = 128, H = 768;
constexpr int C4 = H / 4;
constexpr int KEY_SIZE = 30000, VALUE_SIZE = 10000;

constexpr int VT_N = VALUE_SIZE * H;      // 7,680,000
constexpr int U_N  = B * S * M;           //   262,144

constexpr size_t VT_BYTES = (size_t)VT_N * 2;
constexpr size_t U_BYTES  = (size_t)U_N  * 4;
constexpr size_t WS_NEEDED = VT_BYTES + U_BYTES;      // ~16.4 MB

constexpr int VT_V8     = VT_N / 8;                   // 960,000 ushort8 items
constexpr int NB_PHASEA = 256;                        // 256 blocks * 4 waves = 1024 tiles
constexpr int NB_VT     = VT_V8 / 256;                // 3,750 (exact)
constexpr int NB_PREP   = NB_PHASEA + NB_VT;

typedef short          bf16x8   __attribute__((ext_vector_type(8)));
typedef float          floatx4  __attribute__((ext_vector_type(4)));
typedef unsigned short ushort8v __attribute__((ext_vector_type(8)));

__device__ inline unsigned short f2bf(float f) {
    __hip_bfloat16 h = __float2bfloat16(f);           // RNE
    return *reinterpret_cast<unsigned short*>(&h);
}
__device__ inline float bf2f(unsigned short u) {
    return __uint_as_float((unsigned)u << 16);
}
__device__ inline bf16x8 f8_to_bf8(float4 a, float4 b) {
    bf16x8 r;
    r[0] = (short)f2bf(a.x); r[1] = (short)f2bf(a.y);
    r[2] = (short)f2bf(a.z); r[3] = (short)f2bf(a.w);
    r[4] = (short)f2bf(b.x); r[5] = (short)f2bf(b.y);
    r[6] = (short)f2bf(b.z); r[7] = (short)f2bf(b.w);
    return r;
}

// ---- kernel 1: fused phaseA (MFMA from fp32) + value-table convert ----
__global__ __launch_bounds__(256) void prep_kernel(
    const float* __restrict__ vt,               // [VALUE_SIZE,H] fp32
    const float* __restrict__ kt,               // [KEY_SIZE,H]   fp32
    const float* __restrict__ hs,               // [B,S,H]        fp32
    const int*   __restrict__ wseq,             // [B,M]
    unsigned short* __restrict__ vt_bf,         // [VALUE_SIZE,H] bf16 out
    float*       __restrict__ u_ws)             // [B,S,M] fp32 out
{
    if (blockIdx.x >= NB_PHASEA) {
        // ---- value-table convert: one ushort8 (16B) per thread ----
        int i = (blockIdx.x - NB_PHASEA) * 256 + threadIdx.x;   // < 960,000
        const float4* src = (const float4*)vt + (size_t)i * 2;
        float4 f0 = src[0];
        float4 f1 = src[1];
        ((ushort8v*)vt_bf)[i] = (ushort8v)f8_to_bf8(f0, f1);
        return;
    }

    // ---- phaseA: ONE 16x16 u-tile per wave; 1024 tiles total ----
    const int lane = threadIdx.x & 63;
    const int wave = threadIdx.x >> 6;
    const int tid  = blockIdx.x * 4 + wave;     // 0..1023
    const int bb   = tid >> 8;                  // 256 tiles per b
    const int rr   = tid & 255;
    const int ss0  = (rr >> 3) << 4;            // s-tile * 16
    const int mm0  = (rr & 7) << 4;             // m-tile * 16
    const int l15  = lane & 15;
    const int quad = lane >> 4;

    const float* arow = hs + (size_t)(bb * S + ss0 + l15) * H + quad * 8;
    const int    krow = wseq[bb * M + mm0 + l15];
    const float* brow = kt + (size_t)krow * H + quad * 8;

    floatx4 acc = {0.f, 0.f, 0.f, 0.f};
    #pragma unroll 4
    for (int k = 0; k < H; k += 32) {
        const float4* ap = (const float4*)(arow + k);
        const float4* bp = (const float4*)(brow + k);
        bf16x8 af = f8_to_bf8(ap[0], ap[1]);
        bf16x8 bf = f8_to_bf8(bp[0], bp[1]);
        acc = __builtin_amdgcn_mfma_f32_16x16x32_bf16(af, bf, acc, 0, 0, 0);
    }
    // C/D: col(=m) = lane&15, row(=s) = quad*4 + reg
    float* up = u_ws + (size_t)(bb * S + ss0 + quad * 4) * M + mm0 + l15;
    up[0 * M] = acc[0];
    up[1 * M] = acc[1];
    up[2 * M] = acc[2];
    up[3 * M] = acc[3];
}

// ---- kernel 2: gather + weighted sum + normalize (unchanged from R6) ----
// 192 threads per (b,s). Thread owns 16B h-chunk c = t%96 and parity p = t/96;
// hot loop: 64 iterations of ONE global_load_dwordx4 + 8 cvt/FMA.
__global__ __launch_bounds__(192) void gather_kernel(
    const float* __restrict__ u_ws,             // [B,S,M]
    const int*   __restrict__ lvm,              // [B,S,M]
    const float* __restrict__ mask,             // [B,S,M]
    const unsigned short* __restrict__ vt_bf,   // [VALUE_SIZE,H]
    float*       __restrict__ out)              // [B,S,H]
{
    const int bs = blockIdx.x;
    const int t  = threadIdx.x;       // 0..191
    const int p  = t / 96;            // parity: which half of m
    const int c  = t - p * 96;        // 16B chunk index, 0..95

    __shared__ float delta_s[M];
    __shared__ int   row_s[M];
    __shared__ float merge_s[8][100]; // SoA: [elem][chunk], padded
    __shared__ float dsum_s;

    const float inv_temper = rsqrtf((float)H);
    if (t < M) {
        float u  = u_ws[(size_t)bs * M + t];
        float mk = mask[(size_t)bs * M + t];
        mk = fminf(fmaxf(mk, 0.f), 1.f);
        delta_s[t] = __expf(u * inv_temper) * mk;
        row_s[t]   = lvm[(size_t)bs * M + t];
    }
    __syncthreads();

    // wave 0: denominator (consumed after the epilogue barrier)
    if (t < 64) {
        float d = delta_s[t] + delta_s[t + 64];
        #pragma unroll
        for (int off = 1; off < 64; off <<= 1) d += __shfl_xor(d, off);
        if (t == 0) dsum_s = d + 1e-10f;
    }

    float a0 = 0.f, a1 = 0.f, a2 = 0.f, a3 = 0.f;
    float a4 = 0.f, a5 = 0.f, a6 = 0.f, a7 = 0.f;

    const unsigned short* base = vt_bf + c * 8;
    #pragma unroll 8
    for (int m = p; m < M; m += 2) {
        const float pm = delta_s[m];
        ushort8v v = *(const ushort8v*)(base + (size_t)row_s[m] * H);
        a0 += pm * bf2f(v[0]);
        a1 += pm * bf2f(v[1]);
        a2 += pm * bf2f(v[2]);
        a3 += pm * bf2f(v[3]);
        a4 += pm * bf2f(v[4]);
        a5 += pm * bf2f(v[5]);
        a6 += pm * bf2f(v[6]);
        a7 += pm * bf2f(v[7]);
    }

    if (p == 1) {
        merge_s[0][c] = a0; merge_s[1][c] = a1; merge_s[2][c] = a2; merge_s[3][c] = a3;
        merge_s[4][c] = a4; merge_s[5][c] = a5; merge_s[6][c] = a6; merge_s[7][c] = a7;
    }
    __syncthreads();

    if (p == 0) {
        const float inv_d = 1.0f / dsum_s;
        float4 r0, r1;
        r0.x = (a0 + merge_s[0][c]) * inv_d;
        r0.y = (a1 + merge_s[1][c]) * inv_d;
        r0.z = (a2 + merge_s[2][c]) * inv_d;
        r0.w = (a3 + merge_s[3][c]) * inv_d;
        r1.x = (a4 + merge_s[4][c]) * inv_d;
        r1.y = (a5 + merge_s[5][c]) * inv_d;
        r1.z = (a6 + merge_s[6][c]) * inv_d;
        r1.w = (a7 + merge_s[7][c]) * inv_d;
        float4* og = (float4*)(out + (size_t)bs * H + c * 8);
        og[0] = r0;
        og[1] = r1;
    }
}

// ---- fallback: fused fp32 (only if ws too small) ----
__global__ __launch_bounds__(192) void kvmn_fp32_kernel(
    const int*   __restrict__ word_seq,
    const float* __restrict__ hidden_state,
    const int*   __restrict__ lvm,
    const float* __restrict__ mask,
    const float* __restrict__ key_table,
    const float* __restrict__ value_table,
    float*       __restrict__ out)
{
    const int bs   = blockIdx.x;
    const int b    = bs / S;
    const int t    = threadIdx.x;
    const int lane = t & 63;
    const int wave = t >> 6;

    __shared__ float4 hs4_s[C4];
    __shared__ int    wseq_s[M];
    __shared__ int    row_s[M];
    __shared__ float  mask_s[M];
    __shared__ float4 obuf[3][C4];
    __shared__ float  dsum_s3[3];

    const float4* hs_g4 = (const float4*)(hidden_state + (size_t)bs * H);
    hs4_s[t] = hs_g4[t];
    if (t < M) {
        wseq_s[t] = word_seq[b * M + t];
        row_s[t]  = lvm[(size_t)bs * M + t];
        float mk  = mask[(size_t)bs * M + t];
        mask_s[t] = fminf(fmaxf(mk, 0.f), 1.f);
    }
    __syncthreads();

    const float4 h0 = hs4_s[lane];
    const float4 h1 = hs4_s[lane + 64];
    const float4 h2 = hs4_s[lane + 128];
    const float inv_temper = rsqrtf((float)H);
    const float4* kt4 = (const float4*)key_table;
    const float4* vt4 = (const float4*)value_table;

    float4 a0 = {0.f,0.f,0.f,0.f}, a1 = {0.f,0.f,0.f,0.f}, a2 = {0.f,0.f,0.f,0.f};
    float dsum = 0.f;

    #pragma unroll 2
    for (int m = wave; m < M; m += 3) {
        const float4* kr = kt4 + (size_t)wseq_s[m] * C4;
        const float4* vr = vt4 + (size_t)row_s[m]  * C4;
        const float4 k0 = kr[lane], k1 = kr[lane+64], k2 = kr[lane+128];
        const float4 v0 = vr[lane], v1 = vr[lane+64], v2 = vr[lane+128];
        float dot = h0.x*k0.x + h0.y*k0.y + h0.z*k0.z + h0.w*k0.w
                  + h1.x*k1.x + h1.y*k1.y + h1.z*k1.z + h1.w*k1.w
                  + h2.x*k2.x + h2.y*k2.y + h2.z*k2.z + h2.w*k2.w;
        #pragma unroll
        for (int off = 1; off < 64; off <<= 1) dot += __shfl_xor(dot, off);
        const float delta = __expf(dot * inv_temper) * mask_s[m];
        dsum += delta;
        a0.x += delta*v0.x; a0.y += delta*v0.y; a0.z += delta*v0.z; a0.w += delta*v0.w;
        a1.x += delta*v1.x; a1.y += delta*v1.y; a1.z += delta*v1.z; a1.w += delta*v1.w;
        a2.x += delta*v2.x; a2.y += delta*v2.y; a2.z += delta*v2.z; a2.w += delta*v2.w;
    }
    obuf[wave][lane] = a0; obuf[wave][lane+64] = a1; obuf[wave][lane+128] = a2;
    if (lane == 0) dsum_s3[wave] = dsum;
    __syncthreads();
    const float inv_d = 1.0f / (dsum_s3[0] + dsum_s3[1] + dsum_s3[2] + 1e-10f);
    const float4 r0 = obuf[0][t], r1 = obuf[1][t], r2 = obuf[2][t];
    float4 r;
    r.x = (r0.x+r1.x+r2.x)*inv_d; r.y = (r0.y+r1.y+r2.y)*inv_d;
    r.z = (r0.z+r1.z+r2.z)*inv_d; r.w = (r0.w+r1.w+r2.w)*inv_d;
    ((float4*)(out + (size_t)bs * H))[t] = r;
}

extern "C" void kernel_launch(void* const* d_in, const int* in_sizes, int n_in,
                              void* d_out, int out_size, void* d_ws, size_t ws_size,
                              hipStream_t stream) {
    const int*   word_seq    = (const int*)  d_in[0];
    const float* hidden      = (const float*)d_in[1];
    const int*   lvm         = (const int*)  d_in[2];
    const float* mask        = (const float*)d_in[3];
    const float* key_table   = (const float*)d_in[4];
    const float* value_table = (const float*)d_in[5];
    float* out = (float*)d_out;

    if (ws_size >= WS_NEEDED) {
        unsigned short* vt_bf = (unsigned short*)d_ws;
        float*          u_ws  = (float*)((char*)d_ws + VT_BYTES);

        prep_kernel<<<NB_PREP, 256, 0, stream>>>(
            value_table, key_table, hidden, word_seq, vt_bf, u_ws);
        gather_kernel<<<B * S, 192, 0, stream>>>(
            u_ws, lvm, mask, vt_bf, out);
    } else {
        kvmn_fp32_kernel<<<B * S, 192, 0, stream>>>(
            word_seq, hidden, lvm, mask, key_table, value_table, out);
    }
}